// Round 10
// baseline (308.341 us; speedup 1.0000x reference)
//
#include <hip/hip_runtime.h>
#include <hip/hip_bf16.h>
#include <cstdint>

#define DI __device__ __forceinline__

typedef short bf16x8 __attribute__((ext_vector_type(8)));
typedef float f32x4 __attribute__((ext_vector_type(4)));
typedef float f32x16 __attribute__((ext_vector_type(16)));
typedef unsigned short u16;
typedef unsigned short u16x8 __attribute__((ext_vector_type(8)));

static constexpr int NV = 10, NE = 90, TT = 64;
static constexpr int R1 = 20480;   // 32*10*64 node rows
static constexpr int R2 = 184320;  // 32*90*64 edge rows

DI float bf2f(u16 u) { union { unsigned int i; float f; } x; x.i = ((unsigned int)u) << 16; return x.f; }
DI u16 f2bf(float f) { unsigned int u = __float_as_uint(f); return (u16)((u + 0x7FFF + ((u >> 16) & 1)) >> 16); }
DI float elu(float v) { return v > 0.f ? v : __expf(v) - 1.f; }

#define GLL(srcp, dstp) __builtin_amdgcn_global_load_lds( \
    (const __attribute__((address_space(1))) unsigned int*)(srcp), \
    (__attribute__((address_space(3))) unsigned int*)(dstp), 16, 0, 0)

// ============================================================================
// 128-tile weight packing (R1 GEMMs, r8-verified): PK[(bn*8+kt)*2+p][tid]
//   holds w[k = kt*32+(tid&3)*8+e][n = bn*128 + p*64 + (tid>>2)]
// ============================================================================
__global__ __launch_bounds__(256) void pack4(
    const float* __restrict__ s0, u16* __restrict__ d0,
    const float* __restrict__ s1, u16* __restrict__ d1,
    const float* __restrict__ s2, u16* __restrict__ d2,
    const float* __restrict__ s3, u16* __restrict__ d3) {
    const float* s; u16* d;
    switch (blockIdx.y) {
        case 0: s = s0; d = d0; break;
        case 1: s = s1; d = d1; break;
        case 2: s = s2; d = d2; break;
        default: s = s3; d = d3; break;
    }
    int tid = threadIdx.x;
    int bn = blockIdx.x >> 3, kt = blockIdx.x & 7;
#pragma unroll
    for (int p = 0; p < 2; ++p) {
        int n = bn * 128 + p * 64 + (tid >> 2);
        int k = kt * 32 + (tid & 3) * 8;
        u16x8 pk;
#pragma unroll
        for (int e = 0; e < 8; ++e) pk[e] = f2bf(s[(size_t)(k + e) * 256 + n]);
        *(u16x8*)(d + ((size_t)((bn * 8 + kt) * 2 + p)) * 2048 + (size_t)tid * 8) = pk;
    }
}

// ============================================================================
// 256-tile SWIZZLED packs for gemm256b: linear offset o = kt*8192 + tid2*8
// (tid2 0..1023 over 2 h-halves x 2 p) holds
//   w[k = kt*32 + ((tid2&3) ^ ((tid2>>2)&3))*8 + e][n = tid2>>2]
// i.e. the 16B granule XOR swizzle is baked into the pack so the GEMM's GLL
// source stays linear while LDS granule g of row r holds k-chunk g^(r&3).
// ============================================================================
__global__ __launch_bounds__(256) void pack256s(const float* __restrict__ s,
                                                u16* __restrict__ d) {
    int kt = blockIdx.x;
#pragma unroll
    for (int h = 0; h < 4; ++h) {
        int tid2 = threadIdx.x + h * 256;          // 0..1023
        int n = tid2 >> 2;                          // 0..255
        int g = (tid2 & 3) ^ ((tid2 >> 2) & 3);
        int k = kt * 32 + g * 8;
        u16x8 pk;
#pragma unroll
        for (int e = 0; e < 8; ++e) pk[e] = f2bf(s[(size_t)(k + e) * 256 + n]);
        *(u16x8*)(d + (size_t)kt * 8192 + (size_t)tid2 * 8) = pk;
    }
}

// same, w2a (K=512) with BN1 scale folded
__global__ __launch_bounds__(256) void pack256s_w2a(const float* __restrict__ w2a,
                                                    const float* __restrict__ scsh1,
                                                    u16* __restrict__ d) {
    int kt = blockIdx.x;
#pragma unroll
    for (int h = 0; h < 4; ++h) {
        int tid2 = threadIdx.x + h * 256;
        int n = tid2 >> 2;
        int g = (tid2 & 3) ^ ((tid2 >> 2) & 3);
        int k = kt * 32 + g * 8;
        u16x8 pk;
#pragma unroll
        for (int e = 0; e < 8; ++e)
            pk[e] = f2bf(scsh1[(k + e) & 255] * w2a[(size_t)(k + e) * 256 + n]);
        *(u16x8*)(d + (size_t)kt * 8192 + (size_t)tid2 * 8) = pk;
    }
}

__global__ void zero_stats(float* p, int n) {
    int i = blockIdx.x * 256 + threadIdx.x;
    if (i < n) p[i] = 0.f;
}

__global__ void conv_wo2(const float* __restrict__ src, u16* __restrict__ dst) {
    dst[threadIdx.x] = f2bf(src[threadIdx.x]);
}

// BN1 shift term folded into fc1 bias
__global__ __launch_bounds__(256) void fold_b2a(const float* __restrict__ w2a,
                                                const float* __restrict__ scsh1,
                                                const float* __restrict__ b2a,
                                                float* __restrict__ b2aF) {
    __shared__ float red[256];
    int n = blockIdx.x, tid = threadIdx.x;
    float sc = scsh1[256 + tid];
    float s = sc * w2a[tid * 256 + n] + sc * w2a[(tid + 256) * 256 + n];
    red[tid] = s;
    __syncthreads();
    for (int off2 = 128; off2 > 0; off2 >>= 1) {
        if (tid < off2) red[tid] += red[tid + off2];
        __syncthreads();
    }
    if (tid == 0) b2aF[n] = red[0] + b2a[n];
}

__global__ void stats_final(const float* __restrict__ sums, const float* __restrict__ g,
                            const float* __restrict__ be, float invR, float* __restrict__ scsh) {
    int c = threadIdx.x;
    float mu = sums[c] * invR;
    float var = sums[256 + c] * invR - mu * mu;
    float rs = rsqrtf(var + 1e-5f);
    float sc = g[c] * rs;
    scsh[c] = sc;
    scsh[256 + c] = be[c] - mu * sc;
}

// -------------------- mlp1 fc1: K=4, VALU (verified) -------------------------
__global__ __launch_bounds__(256) void mlp1_fc1(const float* __restrict__ x,
                                                const float* __restrict__ w1a,
                                                const float* __restrict__ b1a,
                                                u16* __restrict__ ha) {
    int tid = threadIdx.x;
    int row = blockIdx.x * 8 + (tid >> 5);
    int ch8 = (tid & 31) * 8;
    int b = row / (NV * TT);
    int v = (row >> 6) % NV;
    int t = row & 63;
    const float* xp = x + ((size_t)(b * TT + t) * NV + v) * 4;
    float x0 = xp[0], x1 = xp[1], x2 = xp[2], x3 = xp[3];
    u16x8 pack;
#pragma unroll
    for (int e = 0; e < 8; ++e) {
        int c = ch8 + e;
        float acc = b1a[c] + x0 * w1a[c] + x1 * w1a[256 + c] + x2 * w1a[512 + c] + x3 * w1a[768 + c];
        pack[e] = f2bf(elu(acc));
    }
    *(u16x8*)(ha + (size_t)row * 256 + ch8) = pack;
}

// ============================================================================
// 128x128 engine (r8-verified, packed-B) — R1 GEMMs only.
// ============================================================================
template <int ACT, bool STATS>   // ACT: 1 elu, 2 relu
__global__ __launch_bounds__(256) void gemm_kernel(const u16* __restrict__ A,
                                                   const u16* __restrict__ Wt,
                                                   const float* __restrict__ bias,
                                                   u16* __restrict__ out,
                                                   int K,
                                                   float* __restrict__ stats) {
    __shared__ u16 As[3][128 * 32];
    __shared__ u16 Bs[3][128 * 32];
    const int tid = threadIdx.x;
    const int lane = tid & 63, wid = tid >> 6;

    int bm, bn;
    {
        int bid = blockIdx.x;
        int xcd = bid & 7, slot = bid >> 3;
        bn = slot & 1;
        bm = xcd + 8 * (slot >> 1);
    }
    const int m0 = bm * 128, n0 = bn * 128;
    const int wm = wid >> 1, wn = wid & 1;

    const int srow = tid >> 2;
    const int scol8 = (tid & 3) * 8;

    size_t abase0 = (size_t)(m0 + srow) * K;
    size_t abase1 = (size_t)(m0 + srow + 64) * K;
    const int NT = K >> 5;
    const size_t bnbase = (size_t)bn * NT * 4096;

    f32x4 acc[4][4];
#pragma unroll
    for (int i = 0; i < 4; ++i)
#pragma unroll
        for (int j = 0; j < 4; ++j) acc[i][j] = (f32x4)0.f;

    const int lrow = lane & 15;
    const int lk8 = (lane >> 4) * 8;

    auto stage = [&](int bf, int k0) {
        const size_t btile = bnbase + (size_t)(k0 >> 5) * 4096 + (size_t)tid * 8;
        GLL(A + abase0 + k0 + scol8, &As[bf][(wid * 64) * 8]);
        GLL(Wt + btile, &Bs[bf][(wid * 64) * 8]);
        GLL(A + abase1 + k0 + scol8, &As[bf][(256 + wid * 64) * 8]);
        GLL(Wt + btile + 2048, &Bs[bf][(256 + wid * 64) * 8]);
    };

    stage(0, 0);
    stage(1, 32);
    for (int kt = 0; kt < NT; ++kt) {
        if (kt + 1 < NT) {
            asm volatile("s_waitcnt vmcnt(4)" ::: "memory");
        } else {
            asm volatile("s_waitcnt vmcnt(0)" ::: "memory");
        }
        __builtin_amdgcn_s_barrier();
        if (kt + 2 < NT) stage((kt + 2) % 3, (kt + 2) * 32);
        __builtin_amdgcn_sched_barrier(0);
        const int buf = kt % 3;
        bf16x8 a[4], b[4];
#pragma unroll
        for (int i = 0; i < 4; ++i)
            a[i] = *(const bf16x8*)&As[buf][(wm * 64 + i * 16 + lrow) * 32 + lk8];
#pragma unroll
        for (int j = 0; j < 4; ++j)
            b[j] = *(const bf16x8*)&Bs[buf][(wn * 64 + j * 16 + lrow) * 32 + lk8];
#pragma unroll
        for (int i = 0; i < 4; ++i)
#pragma unroll
            for (int j = 0; j < 4; ++j)
                acc[i][j] = __builtin_amdgcn_mfma_f32_16x16x32_bf16(a[i], b[j], acc[i][j], 0, 0, 0);
    }

    float bv[4], sv[4], qv[4];
#pragma unroll
    for (int j = 0; j < 4; ++j) {
        bv[j] = bias[n0 + wn * 64 + j * 16 + lrow];
        if constexpr (STATS) { sv[j] = 0.f; qv[j] = 0.f; }
    }
#pragma unroll
    for (int i = 0; i < 4; ++i) {
#pragma unroll
        for (int j = 0; j < 4; ++j) {
            int col = n0 + wn * 64 + j * 16 + lrow;
#pragma unroll
            for (int r = 0; r < 4; ++r) {
                int row = m0 + wm * 64 + i * 16 + (lane >> 4) * 4 + r;
                float v = acc[i][j][r] + bv[j];
                v = (ACT == 1) ? elu(v) : (v > 0.f ? v : 0.f);
                if constexpr (STATS) { sv[j] += v; qv[j] += v * v; }
                out[(size_t)row * 256 + col] = f2bf(v);
            }
        }
    }
    if constexpr (STATS) {
#pragma unroll
        for (int j = 0; j < 4; ++j) {
            float s = sv[j], q_ = qv[j];
            s += __shfl_xor(s, 16); q_ += __shfl_xor(q_, 16);
            s += __shfl_xor(s, 32); q_ += __shfl_xor(q_, 32);
            if ((lane >> 4) == 0) {
                int col = n0 + wn * 64 + j * 16 + lrow;
                atomicAdd(&stats[col], s);
                atomicAdd(&stats[256 + col], q_);
            }
        }
    }
}

// ============================================================================
// gemm256b — R2 GEMMs. Block 256x256, 4 waves (2x2), wave-tile 128x128,
// mfma_f32_32x32x16_bf16, acc[4][4] f32x16 (256 AGPR). LDS-read port pressure
// per FLOP cut 1.5x vs 128x64 wave tiles (the measured limiter).
//   LDS: As/Bs[3][256*32] u16 = 96 KB, 1 block/CU.
//   Staging: 8 GLL/thread/step (4 A rounds + 4 B rounds, 4KB each), linear
//   dest; granule swizzle applied on SOURCE (A: scol; B: baked into pack256s).
//   Fragment reads: granule g = (kk*2 + (lane>>5)) ^ (lane&3).
//   Pipeline: 3-buf, counted vmcnt(8), sched_barrier(0) (r7/r8-verified).
//   C/D mapping (m74/m101): col=lane&31, row=(reg&3)+8*(reg>>2)+4*(lane>>5).
// ============================================================================
template <bool GATHER, bool STATS>
__global__ __launch_bounds__(256) void gemm256b(const u16* __restrict__ A,
                                                const u16* __restrict__ PK,
                                                const float* __restrict__ bias,
                                                u16* __restrict__ out,
                                                int K,
                                                float* __restrict__ stats) {
    __shared__ u16 As[3][256 * 32];
    __shared__ u16 Bs[3][256 * 32];
    const int tid = threadIdx.x;
    const int lane = tid & 63, wid = tid >> 6;   // 4 waves

    const int bm = (blockIdx.x & 7) * 90 + (blockIdx.x >> 3);  // chunked XCD map
    const int m0 = bm * 256;
    const int wm = wid >> 1, wn = wid & 1;       // 2x2 wave grid, 128x128 tiles

    const int srow = tid >> 2;                   // 0..63 per staging round
    const int sswz = ((tid & 3) ^ ((tid >> 2) & 3)) * 8;   // swizzled k-granule

    size_t ab[4], sb[4], rb[4];
    if constexpr (GATHER) {
#pragma unroll
        for (int q = 0; q < 4; ++q) {
            int m = m0 + q * 64 + srow;
            int t = m & 63, be = m >> 6, e = be % NE, b = be / NE;
            int s = e / 9, kk = e - s * 9, r = kk + (kk >= s ? 1 : 0);
            sb[q] = ((size_t)((b * NV + s) * TT + t)) * 256;
            rb[q] = ((size_t)((b * NV + r) * TT + t)) * 256;
        }
    } else {
#pragma unroll
        for (int q = 0; q < 4; ++q) ab[q] = (size_t)(m0 + q * 64 + srow) * K;
    }
    const int NT = K >> 5;

    f32x16 acc[4][4];
#pragma unroll
    for (int bi = 0; bi < 4; ++bi)
#pragma unroll
        for (int bj = 0; bj < 4; ++bj) acc[bi][bj] = (f32x16)0.f;

    auto stage = [&](int bf, int k0) {
        const size_t btile = (size_t)(k0 >> 5) * 8192;
#pragma unroll
        for (int q = 0; q < 4; ++q) {
            const u16* a_;
            if constexpr (GATHER) {
                a_ = A + (k0 < 256 ? sb[q] : rb[q]) + (k0 & 255) + sswz;
            } else {
                a_ = A + ab[q] + k0 + sswz;
            }
            GLL(a_, &As[bf][q * 2048 + wid * 512]);
            GLL(PK + btile + q * 2048 + (size_t)tid * 8, &Bs[bf][q * 2048 + wid * 512]);
        }
    };

    const int l31 = lane & 31;
    const int lh = lane >> 5;        // k-half
    const int lx = lane & 3;         // row&3 for granule swizzle

    stage(0, 0);
    stage(1, 32);
    for (int kt = 0; kt < NT; ++kt) {
        if (kt + 1 < NT) {
            asm volatile("s_waitcnt vmcnt(8)" ::: "memory");
        } else {
            asm volatile("s_waitcnt vmcnt(0)" ::: "memory");
        }
        __builtin_amdgcn_s_barrier();
        if (kt + 2 < NT) stage((kt + 2) % 3, (kt + 2) * 32);
        __builtin_amdgcn_sched_barrier(0);
        const int buf = kt % 3;
#pragma unroll
        for (int kk = 0; kk < 2; ++kk) {
            const int g = (kk * 2 + lh) ^ lx;          // swizzled granule
            bf16x8 a[4], b[4];
#pragma unroll
            for (int bi = 0; bi < 4; ++bi) {
                int r = wm * 128 + bi * 32 + l31;
                a[bi] = *(const bf16x8*)&As[buf][r * 32 + g * 8];
            }
#pragma unroll
            for (int bj = 0; bj < 4; ++bj) {
                int rn = wn * 128 + bj * 32 + l31;
                b[bj] = *(const bf16x8*)&Bs[buf][rn * 32 + g * 8];
            }
#pragma unroll
            for (int bi = 0; bi < 4; ++bi)
#pragma unroll
                for (int bj = 0; bj < 4; ++bj)
                    acc[bi][bj] = __builtin_amdgcn_mfma_f32_32x32x16_bf16(a[bi], b[bj], acc[bi][bj], 0, 0, 0);
        }
    }

    // ---- epilogue: bias + elu (+stats) + store ----
#pragma unroll
    for (int bj = 0; bj < 4; ++bj) {
        int col = wn * 128 + bj * 32 + l31;
        float bv = bias[col];
        float sv = 0.f, qv = 0.f;
#pragma unroll
        for (int bi = 0; bi < 4; ++bi) {
            int rbase = m0 + wm * 128 + bi * 32 + 4 * lh;
#pragma unroll
            for (int reg = 0; reg < 16; ++reg) {
                int row = rbase + (reg & 3) + 8 * (reg >> 2);
                float v = acc[bi][bj][reg] + bv;
                v = elu(v);
                if constexpr (STATS) { sv += v; qv += v * v; }
                out[(size_t)row * 256 + col] = f2bf(v);
            }
        }
        if constexpr (STATS) {
            sv += __shfl_xor(sv, 32);
            qv += __shfl_xor(qv, 32);
            if (lh == 0) {
                atomicAdd(&stats[col], sv);
                atomicAdd(&stats[256 + col], qv);
            }
        }
    }
}

// -------------------- elementwise affine + relu (BN3) ------------------------
__global__ __launch_bounds__(256) void norm_affine_relu(const u16* __restrict__ in,
                                                        const float* __restrict__ scsh,
                                                        u16* __restrict__ out, int n8) {
    int i = blockIdx.x * 256 + threadIdx.x;
    if (i >= n8) return;
    size_t base = (size_t)i * 8;
    int ch8 = (int)(base & 255);
    u16x8 v = *(const u16x8*)(in + base);
    u16x8 o;
#pragma unroll
    for (int e = 0; e < 8; ++e) {
        float f = bf2f(v[e]);
        f = scsh[ch8 + e] * f + scsh[256 + ch8 + e];
        o[e] = f2bf(f > 0.f ? f : 0.f);
    }
    *(u16x8*)(out + base) = o;
}

// -------------------- edge2node: incidence sum + BN2 affine (verified) -------
__global__ __launch_bounds__(256) void edge2node(const u16* __restrict__ h2,
                                                 const float* __restrict__ scsh2,
                                                 u16* __restrict__ n1) {
    int tid = threadIdx.x;
    int row = blockIdx.x * 8 + (tid >> 5);
    int ch8 = (tid & 31) * 8;
    int t = row & 63;
    int bv = row >> 6;
    int v = bv % NV;
    int b = bv / NV;
    float acc[8] = {0, 0, 0, 0, 0, 0, 0, 0};
#pragma unroll
    for (int i = 0; i < 9; ++i) {
        int s = i + (i >= v ? 1 : 0);
        int e = s * 9 + (v < s ? v : v - 1);
        u16x8 vv = *(const u16x8*)(h2 + ((size_t)((b * NE + e) * TT + t)) * 256 + ch8);
#pragma unroll
        for (int k = 0; k < 8; ++k) acc[k] += bf2f(vv[k]);
    }
    const float inv9 = 1.f / 9.f;
    u16x8 o;
#pragma unroll
    for (int k = 0; k < 8; ++k) {
        int c = ch8 + k;
        o[k] = f2bf(scsh2[c] * (acc[k] * inv9) + scsh2[256 + c]);
    }
    *(u16x8*)(n1 + (size_t)row * 256 + ch8) = o;
}

// -------------------- final head: dot(a2_row, wo2) + bo2 (verified) ----------
__global__ __launch_bounds__(256) void head2(const u16* __restrict__ a2,
                                             const u16* __restrict__ wo2t,
                                             const float* __restrict__ bo2,
                                             float* __restrict__ out) {
    int tid = threadIdx.x;
    int row = blockIdx.x * 8 + (tid >> 5);
    int l32 = tid & 31;
    int ch8 = l32 * 8;
    u16x8 a = *(const u16x8*)(a2 + (size_t)row * 256 + ch8);
    u16x8 w = *(const u16x8*)(wo2t + ch8);
    float p = 0.f;
#pragma unroll
    for (int k = 0; k < 8; ++k) p += bf2f(a[k]) * bf2f(w[k]);
#pragma unroll
    for (int off = 16; off > 0; off >>= 1) p += __shfl_down(p, off, 32);
    if (l32 == 0) {
        int b = row / (NV * TT);
        int v = (row >> 6) % NV;
        int t = row & 63;
        out[(size_t)(b * TT + t) * NV + v] = p + bo2[0];
    }
}

extern "C" void kernel_launch(void* const* d_in, const int* in_sizes, int n_in,
                              void* d_out, int out_size, void* d_ws, size_t ws_size,
                              hipStream_t stream) {
    const float* x   = (const float*)d_in[0];
    const float* w1a = (const float*)d_in[1];
    const float* b1a = (const float*)d_in[2];
    const float* w1b = (const float*)d_in[3];
    const float* b1b = (const float*)d_in[4];
    const float* g1  = (const float*)d_in[5];
    const float* be1 = (const float*)d_in[6];
    const float* w2a = (const float*)d_in[7];
    const float* b2a = (const float*)d_in[8];
    const float* w2b = (const float*)d_in[9];
    const float* b2b = (const float*)d_in[10];
    const float* g2  = (const float*)d_in[11];
    const float* be2 = (const float*)d_in[12];
    const float* w3a = (const float*)d_in[13];
    const float* b3a = (const float*)d_in[14];
    const float* w3b = (const float*)d_in[15];
    const float* b3b = (const float*)d_in[16];
    const float* g3  = (const float*)d_in[17];
    const float* be3 = (const float*)d_in[18];
    const float* wo1 = (const float*)d_in[19];
    const float* bo1 = (const float*)d_in[20];
    const float* wo2 = (const float*)d_in[21];
    const float* bo2 = (const float*)d_in[22];
    float* out = (float*)d_out;

    char* ws = (char*)d_ws;
    size_t off = 0;
    auto alloc = [&](size_t bytes) {
        void* p = ws + off;
        off = (off + bytes + 255) & ~(size_t)255;
        return p;
    };
    u16* w1bP = (u16*)alloc(2 * 8 * 4096 * 2);     // 128-tile pack, K=256
    u16* w3aP = (u16*)alloc(2 * 8 * 4096 * 2);
    u16* w3bP = (u16*)alloc(2 * 8 * 4096 * 2);
    u16* wo1P = (u16*)alloc(2 * 8 * 4096 * 2);
    u16* w2aP = (u16*)alloc(16 * 8192 * 2);        // 256-tile swz pack, K=512
    u16* w2bP = (u16*)alloc(8 * 8192 * 2);         // 256-tile swz pack, K=256
    u16* wo2T = (u16*)alloc(256 * 2);
    float* sums  = (float*)alloc(3 * 512 * 4);
    float* scsh1 = (float*)alloc(512 * 4);
    float* scsh2 = (float*)alloc(512 * 4);
    float* scsh3 = (float*)alloc(512 * 4);
    float* b2aF  = (float*)alloc(256 * 4);
    u16* S0 = (u16*)alloc((size_t)R1 * 256 * 2);
    u16* S1 = (u16*)alloc((size_t)R1 * 256 * 2);
    u16* S2 = (u16*)alloc((size_t)R1 * 256 * 2);
    u16* BIG1 = (u16*)alloc((size_t)R2 * 256 * 2);
    u16* BIG2 = (u16*)alloc((size_t)R2 * 256 * 2);

    dim3 pgrid(16, 4);
    pack4<<<pgrid, 256, 0, stream>>>(w1b, w1bP, w3a, w3aP, w3b, w3bP, wo1, wo1P);
    pack256s<<<8, 256, 0, stream>>>(w2b, w2bP);
    zero_stats<<<6, 256, 0, stream>>>(sums, 3 * 512);
    conv_wo2<<<1, 256, 0, stream>>>(wo2, wo2T);

    // mlp1: fc1 (VALU) + fc2 GEMM with fused stats
    mlp1_fc1<<<R1 / 8, 256, 0, stream>>>(x, w1a, b1a, S0);
    gemm_kernel<1, true><<<(R1 / 128) * 2, 256, 0, stream>>>(S0, w1bP, b1b, S1, 256, sums);
    stats_final<<<1, 256, 0, stream>>>(sums, g1, be1, 1.f / R1, scsh1);
    pack256s_w2a<<<16, 256, 0, stream>>>(w2a, scsh1, w2aP);
    fold_b2a<<<256, 256, 0, stream>>>(w2a, scsh1, b2a, b2aF);

    // mlp2: 256x256 fat-wave engine — gather fc1 (BN1 folded), fc2 + stats
    gemm256b<true, false><<<R2 / 256, 256, 0, stream>>>(S1, w2aP, b2aF, BIG1, 512, nullptr);
    gemm256b<false, true><<<R2 / 256, 256, 0, stream>>>(BIG1, w2bP, b2b, BIG2, 256, sums + 512);
    stats_final<<<1, 256, 0, stream>>>(sums + 512, g2, be2, 1.f / R2, scsh2);

    // edge2node (BN2 affine folded in)
    edge2node<<<R1 / 8, 256, 0, stream>>>(BIG2, scsh2, S0);

    // mlp3: two GEMMs, stats fused into fc2
    gemm_kernel<1, false><<<(R1 / 128) * 2, 256, 0, stream>>>(S0, w3aP, b3a, S1, 256, nullptr);
    gemm_kernel<1, true><<<(R1 / 128) * 2, 256, 0, stream>>>(S1, w3bP, b3b, S2, 256, sums + 1024);
    stats_final<<<1, 256, 0, stream>>>(sums + 1024, g3, be3, 1.f / R1, scsh3);

    // head: BN3 affine+relu, wo1 GEMM (relu), dot wo2
    norm_affine_relu<<<(R1 * 32 + 255) / 256, 256, 0, stream>>>(S2, scsh3, S0, R1 * 32);
    gemm_kernel<2, false><<<(R1 / 128) * 2, 256, 0, stream>>>(S0, wo1P, bo1, S1, 256, nullptr);
    head2<<<R1 / 8, 256, 0, stream>>>(S1, wo2T, bo2, out);
}

// Round 11
// 244.928 us; speedup vs baseline: 1.2589x; 1.2589x over previous
//
#include <hip/hip_runtime.h>
#include <hip/hip_bf16.h>
#include <cstdint>

#define DI __device__ __forceinline__

typedef short bf16x8 __attribute__((ext_vector_type(8)));
typedef float f32x4 __attribute__((ext_vector_type(4)));
typedef unsigned short u16;
typedef unsigned short u16x8 __attribute__((ext_vector_type(8)));

static constexpr int NV = 10, NE = 90, TT = 64;
static constexpr int R1 = 20480;   // 32*10*64 node rows
static constexpr int R2 = 184320;  // 32*90*64 edge rows

DI float bf2f(u16 u) { union { unsigned int i; float f; } x; x.i = ((unsigned int)u) << 16; return x.f; }
DI u16 f2bf(float f) { unsigned int u = __float_as_uint(f); return (u16)((u + 0x7FFF + ((u >> 16) & 1)) >> 16); }
DI float elu(float v) { return v > 0.f ? v : __expf(v) - 1.f; }

#define GLL(srcp, dstp) __builtin_amdgcn_global_load_lds( \
    (const __attribute__((address_space(1))) unsigned int*)(srcp), \
    (__attribute__((address_space(3))) unsigned int*)(dstp), 16, 0, 0)

// ============================================================================
// 128-tile weight packing (R1 GEMMs, r8-verified): PK[(bn*8+kt)*2+p][tid]
//   holds w[k = kt*32+(tid&3)*8+e][n = bn*128 + p*64 + (tid>>2)]
// ============================================================================
__global__ __launch_bounds__(256) void pack4(
    const float* __restrict__ s0, u16* __restrict__ d0,
    const float* __restrict__ s1, u16* __restrict__ d1,
    const float* __restrict__ s2, u16* __restrict__ d2,
    const float* __restrict__ s3, u16* __restrict__ d3) {
    const float* s; u16* d;
    switch (blockIdx.y) {
        case 0: s = s0; d = d0; break;
        case 1: s = s1; d = d1; break;
        case 2: s = s2; d = d2; break;
        default: s = s3; d = d3; break;
    }
    int tid = threadIdx.x;
    int bn = blockIdx.x >> 3, kt = blockIdx.x & 7;
#pragma unroll
    for (int p = 0; p < 2; ++p) {
        int n = bn * 128 + p * 64 + (tid >> 2);
        int k = kt * 32 + (tid & 3) * 8;
        u16x8 pk;
#pragma unroll
        for (int e = 0; e < 8; ++e) pk[e] = f2bf(s[(size_t)(k + e) * 256 + n]);
        *(u16x8*)(d + ((size_t)((bn * 8 + kt) * 2 + p)) * 2048 + (size_t)tid * 8) = pk;
    }
}

// ============================================================================
// 256-wide packs (r9-verified, NON-swizzled): granule at
//   [kt][p][tid2] holds w[k = kt*32+(tid2&3)*8+e][n = p*128 + (tid2>>2)]
// GEMM GLL source = PK + kt*8192 + tid*8 (+4096 for p=1): contiguous 8KB runs.
// ============================================================================
__global__ __launch_bounds__(256) void pack256(const float* __restrict__ s,
                                               u16* __restrict__ d) {
    int kt = blockIdx.x;
#pragma unroll
    for (int h = 0; h < 2; ++h) {
        int tid2 = threadIdx.x + h * 256;
#pragma unroll
        for (int p = 0; p < 2; ++p) {
            int n = p * 128 + (tid2 >> 2);
            int k = kt * 32 + (tid2 & 3) * 8;
            u16x8 pk;
#pragma unroll
            for (int e = 0; e < 8; ++e) pk[e] = f2bf(s[(size_t)(k + e) * 256 + n]);
            *(u16x8*)(d + ((size_t)(kt * 2 + p)) * 4096 + (size_t)tid2 * 8) = pk;
        }
    }
}

// w2a 256-wide pack, K=512, BN1 scale folded
__global__ __launch_bounds__(256) void pack256_w2a(const float* __restrict__ w2a,
                                                   const float* __restrict__ scsh1,
                                                   u16* __restrict__ d) {
    int kt = blockIdx.x;
#pragma unroll
    for (int h = 0; h < 2; ++h) {
        int tid2 = threadIdx.x + h * 256;
#pragma unroll
        for (int p = 0; p < 2; ++p) {
            int n = p * 128 + (tid2 >> 2);
            int k = kt * 32 + (tid2 & 3) * 8;
            u16x8 pk;
#pragma unroll
            for (int e = 0; e < 8; ++e)
                pk[e] = f2bf(scsh1[(k + e) & 255] * w2a[(size_t)(k + e) * 256 + n]);
            *(u16x8*)(d + ((size_t)(kt * 2 + p)) * 4096 + (size_t)tid2 * 8) = pk;
        }
    }
}

__global__ void zero_stats(float* p, int n) {
    int i = blockIdx.x * 256 + threadIdx.x;
    if (i < n) p[i] = 0.f;
}

__global__ void conv_wo2(const float* __restrict__ src, u16* __restrict__ dst) {
    dst[threadIdx.x] = f2bf(src[threadIdx.x]);
}

// BN1 shift term folded into fc1 bias
__global__ __launch_bounds__(256) void fold_b2a(const float* __restrict__ w2a,
                                                const float* __restrict__ scsh1,
                                                const float* __restrict__ b2a,
                                                float* __restrict__ b2aF) {
    __shared__ float red[256];
    int n = blockIdx.x, tid = threadIdx.x;
    float sc = scsh1[256 + tid];
    float s = sc * w2a[tid * 256 + n] + sc * w2a[(tid + 256) * 256 + n];
    red[tid] = s;
    __syncthreads();
    for (int off2 = 128; off2 > 0; off2 >>= 1) {
        if (tid < off2) red[tid] += red[tid + off2];
        __syncthreads();
    }
    if (tid == 0) b2aF[n] = red[0] + b2a[n];
}

__global__ void stats_final(const float* __restrict__ sums, const float* __restrict__ g,
                            const float* __restrict__ be, float invR, float* __restrict__ scsh) {
    int c = threadIdx.x;
    float mu = sums[c] * invR;
    float var = sums[256 + c] * invR - mu * mu;
    float rs = rsqrtf(var + 1e-5f);
    float sc = g[c] * rs;
    scsh[c] = sc;
    scsh[256 + c] = be[c] - mu * sc;
}

// -------------------- mlp1 fc1: K=4, VALU (verified) -------------------------
__global__ __launch_bounds__(256) void mlp1_fc1(const float* __restrict__ x,
                                                const float* __restrict__ w1a,
                                                const float* __restrict__ b1a,
                                                u16* __restrict__ ha) {
    int tid = threadIdx.x;
    int row = blockIdx.x * 8 + (tid >> 5);
    int ch8 = (tid & 31) * 8;
    int b = row / (NV * TT);
    int v = (row >> 6) % NV;
    int t = row & 63;
    const float* xp = x + ((size_t)(b * TT + t) * NV + v) * 4;
    float x0 = xp[0], x1 = xp[1], x2 = xp[2], x3 = xp[3];
    u16x8 pack;
#pragma unroll
    for (int e = 0; e < 8; ++e) {
        int c = ch8 + e;
        float acc = b1a[c] + x0 * w1a[c] + x1 * w1a[256 + c] + x2 * w1a[512 + c] + x3 * w1a[768 + c];
        pack[e] = f2bf(elu(acc));
    }
    *(u16x8*)(ha + (size_t)row * 256 + ch8) = pack;
}

// ============================================================================
// 128x128 engine (r8-verified, packed-B) — R1 GEMMs only.
// ============================================================================
template <int ACT, bool STATS>   // ACT: 1 elu, 2 relu
__global__ __launch_bounds__(256) void gemm_kernel(const u16* __restrict__ A,
                                                   const u16* __restrict__ Wt,
                                                   const float* __restrict__ bias,
                                                   u16* __restrict__ out,
                                                   int K,
                                                   float* __restrict__ stats) {
    __shared__ u16 As[3][128 * 32];
    __shared__ u16 Bs[3][128 * 32];
    const int tid = threadIdx.x;
    const int lane = tid & 63, wid = tid >> 6;

    int bm, bn;
    {
        int bid = blockIdx.x;
        int xcd = bid & 7, slot = bid >> 3;
        bn = slot & 1;
        bm = xcd + 8 * (slot >> 1);
    }
    const int m0 = bm * 128, n0 = bn * 128;
    const int wm = wid >> 1, wn = wid & 1;

    const int srow = tid >> 2;
    const int scol8 = (tid & 3) * 8;

    size_t abase0 = (size_t)(m0 + srow) * K;
    size_t abase1 = (size_t)(m0 + srow + 64) * K;
    const int NT = K >> 5;
    const size_t bnbase = (size_t)bn * NT * 4096;

    f32x4 acc[4][4];
#pragma unroll
    for (int i = 0; i < 4; ++i)
#pragma unroll
        for (int j = 0; j < 4; ++j) acc[i][j] = (f32x4)0.f;

    const int lrow = lane & 15;
    const int lk8 = (lane >> 4) * 8;

    auto stage = [&](int bf, int k0) {
        const size_t btile = bnbase + (size_t)(k0 >> 5) * 4096 + (size_t)tid * 8;
        GLL(A + abase0 + k0 + scol8, &As[bf][(wid * 64) * 8]);
        GLL(Wt + btile, &Bs[bf][(wid * 64) * 8]);
        GLL(A + abase1 + k0 + scol8, &As[bf][(256 + wid * 64) * 8]);
        GLL(Wt + btile + 2048, &Bs[bf][(256 + wid * 64) * 8]);
    };

    stage(0, 0);
    stage(1, 32);
    for (int kt = 0; kt < NT; ++kt) {
        if (kt + 1 < NT) {
            asm volatile("s_waitcnt vmcnt(4)" ::: "memory");
        } else {
            asm volatile("s_waitcnt vmcnt(0)" ::: "memory");
        }
        __builtin_amdgcn_s_barrier();
        if (kt + 2 < NT) stage((kt + 2) % 3, (kt + 2) * 32);
        __builtin_amdgcn_sched_barrier(0);
        const int buf = kt % 3;
        bf16x8 a[4], b[4];
#pragma unroll
        for (int i = 0; i < 4; ++i)
            a[i] = *(const bf16x8*)&As[buf][(wm * 64 + i * 16 + lrow) * 32 + lk8];
#pragma unroll
        for (int j = 0; j < 4; ++j)
            b[j] = *(const bf16x8*)&Bs[buf][(wn * 64 + j * 16 + lrow) * 32 + lk8];
#pragma unroll
        for (int i = 0; i < 4; ++i)
#pragma unroll
            for (int j = 0; j < 4; ++j)
                acc[i][j] = __builtin_amdgcn_mfma_f32_16x16x32_bf16(a[i], b[j], acc[i][j], 0, 0, 0);
    }

    float bv[4], sv[4], qv[4];
#pragma unroll
    for (int j = 0; j < 4; ++j) {
        bv[j] = bias[n0 + wn * 64 + j * 16 + lrow];
        if constexpr (STATS) { sv[j] = 0.f; qv[j] = 0.f; }
    }
#pragma unroll
    for (int i = 0; i < 4; ++i) {
#pragma unroll
        for (int j = 0; j < 4; ++j) {
            int col = n0 + wn * 64 + j * 16 + lrow;
#pragma unroll
            for (int r = 0; r < 4; ++r) {
                int row = m0 + wm * 64 + i * 16 + (lane >> 4) * 4 + r;
                float v = acc[i][j][r] + bv[j];
                v = (ACT == 1) ? elu(v) : (v > 0.f ? v : 0.f);
                if constexpr (STATS) { sv[j] += v; qv[j] += v * v; }
                out[(size_t)row * 256 + col] = f2bf(v);
            }
        }
    }
    if constexpr (STATS) {
#pragma unroll
        for (int j = 0; j < 4; ++j) {
            float s = sv[j], q_ = qv[j];
            s += __shfl_xor(s, 16); q_ += __shfl_xor(q_, 16);
            s += __shfl_xor(s, 32); q_ += __shfl_xor(q_, 32);
            if ((lane >> 4) == 0) {
                int col = n0 + wn * 64 + j * 16 + lrow;
                atomicAdd(&stats[col], s);
                atomicAdd(&stats[256 + col], q_);
            }
        }
    }
}

// ============================================================================
// mlp2_fused — gather-fc1 -> H1 (LDS) -> fc2, one kernel. Eliminates BIG1
// (94MB write + 94MB read of L2-miss traffic, the r1..r10 invariant bound).
//   Block: 128 edge-rows x N=256 full. 512 threads / 8 waves (2M x 4N grid,
//   wave tile 64x64, acc[4][4] f32x4) — 2 waves/SIMD (r9-proven occupancy).
//   LDS: As[3][8KB] + Bs[3][16KB] + H1[64KB] = 136KB, 1 block/CU.
//   Pipeline: r8's 3-buf counted-vmcnt (3 GLL/stage fc1 -> vmcnt(3);
//   2 GLL/stage fc2 -> vmcnt(2)); sched_barrier(0) after stage.
//   H1 swizzle (both sides, rule #21): 16B granule slot = (col>>3) ^ (row&7);
//   write in fc1 epilogue, read as fc2 A-fragment -> ~2-way banks (free).
//   fc2 epilogue: bias+elu, fused BN2 stats, store BIG2.
//   Batch-XCD swizzle: 1440 = 8 x (4*45), batch -> fixed XCD.
// ============================================================================
__global__ __launch_bounds__(512) void mlp2_fused(const u16* __restrict__ A,
                                                  const u16* __restrict__ PB1,
                                                  const float* __restrict__ bias1,
                                                  const u16* __restrict__ PB2,
                                                  const float* __restrict__ bias2,
                                                  u16* __restrict__ out,
                                                  float* __restrict__ stats) {
    __shared__ u16 As[3][128 * 32];    // 24 KB
    __shared__ u16 Bs[3][256 * 32];    // 48 KB
    __shared__ u16 H1[128 * 256];      // 64 KB

    const int tid = threadIdx.x;
    const int lane = tid & 63, wid = tid >> 6;     // 8 waves

    int bid = blockIdx.x;
    int xcd = bid & 7, slot = bid >> 3;            // 1440 = 8*180
    int batch = xcd + 8 * (slot / 45);
    int bm = batch * 45 + (slot % 45);
    const int m0 = bm * 128;
    const int wm = wid >> 2, wn = wid & 3;          // 2M x 4N wave grid

    // per-thread gather bases: staged row = tid>>2, k-chunk = tid&3
    size_t sb, rb;
    {
        int m = m0 + (tid >> 2);
        int t = m & 63, be = m >> 6, e = be % NE, b = be / NE;
        int s = e / 9, kk = e - s * 9, r = kk + (kk >= s ? 1 : 0);
        sb = ((size_t)((b * NV + s) * TT + t)) * 256 + (tid & 3) * 8;
        rb = ((size_t)((b * NV + r) * TT + t)) * 256 + (tid & 3) * 8;
    }

    const int lrow = lane & 15;
    const int lk8 = (lane >> 4) * 8;

    f32x4 acc[4][4];
#pragma unroll
    for (int i = 0; i < 4; ++i)
#pragma unroll
        for (int j = 0; j < 4; ++j) acc[i][j] = (f32x4)0.f;

    auto stage1 = [&](int bf, int k0) {
        GLL(A + (k0 < 256 ? sb : rb) + (k0 & 255), &As[bf][tid * 8]);
        const u16* b_ = PB1 + (size_t)(k0 >> 5) * 8192 + (size_t)tid * 8;
        GLL(b_, &Bs[bf][tid * 8]);
        GLL(b_ + 4096, &Bs[bf][4096 + tid * 8]);
    };

    // ---------------- fc1: K=512, NT=16 ----------------
    stage1(0, 0);
    stage1(1, 32);
    for (int kt = 0; kt < 16; ++kt) {
        if (kt + 1 < 16) {
            asm volatile("s_waitcnt vmcnt(3)" ::: "memory");
        } else {
            asm volatile("s_waitcnt vmcnt(0)" ::: "memory");
        }
        __builtin_amdgcn_s_barrier();
        if (kt + 2 < 16) stage1((kt + 2) % 3, (kt + 2) * 32);
        __builtin_amdgcn_sched_barrier(0);
        const int buf = kt % 3;
        bf16x8 a[4], b[4];
#pragma unroll
        for (int i = 0; i < 4; ++i)
            a[i] = *(const bf16x8*)&As[buf][(wm * 64 + i * 16 + lrow) * 32 + lk8];
#pragma unroll
        for (int j = 0; j < 4; ++j)
            b[j] = *(const bf16x8*)&Bs[buf][(wn * 64 + j * 16 + lrow) * 32 + lk8];
#pragma unroll
        for (int i = 0; i < 4; ++i)
#pragma unroll
            for (int j = 0; j < 4; ++j)
                acc[i][j] = __builtin_amdgcn_mfma_f32_16x16x32_bf16(a[i], b[j], acc[i][j], 0, 0, 0);
    }

    // ---- fc1 epilogue -> H1 (swizzled ds_write) ----
#pragma unroll
    for (int j = 0; j < 4; ++j) {
        int c = wn * 64 + j * 16 + lrow;
        float bv = bias1[c];
        int gx = c >> 3;
        int cl = c & 7;
#pragma unroll
        for (int i = 0; i < 4; ++i) {
#pragma unroll
            for (int r = 0; r < 4; ++r) {
                int m = wm * 64 + i * 16 + (lane >> 4) * 4 + r;
                float v = elu(acc[i][j][r] + bv);
                H1[m * 256 + ((gx ^ (m & 7)) << 3) + cl] = f2bf(v);
            }
        }
    }
    __syncthreads();   // H1 published; fc1 reads of Bs finished -> safe to re-stage

    // ---------------- fc2: K=256, NT=8, A from H1 ----------------
#pragma unroll
    for (int i = 0; i < 4; ++i)
#pragma unroll
        for (int j = 0; j < 4; ++j) acc[i][j] = (f32x4)0.f;

    auto stage2 = [&](int bf, int k0) {
        const u16* b_ = PB2 + (size_t)(k0 >> 5) * 8192 + (size_t)tid * 8;
        GLL(b_, &Bs[bf][tid * 8]);
        GLL(b_ + 4096, &Bs[bf][4096 + tid * 8]);
    };

    stage2(0, 0);
    stage2(1, 32);
    for (int kt = 0; kt < 8; ++kt) {
        if (kt + 1 < 8) {
            asm volatile("s_waitcnt vmcnt(2)" ::: "memory");
        } else {
            asm volatile("s_waitcnt vmcnt(0)" ::: "memory");
        }
        __builtin_amdgcn_s_barrier();
        if (kt + 2 < 8) stage2((kt + 2) % 3, (kt + 2) * 32);
        __builtin_amdgcn_sched_barrier(0);
        const int buf = kt % 3;
        const int k0 = kt * 32;
        bf16x8 a[4], b[4];
#pragma unroll
        for (int i = 0; i < 4; ++i) {
            int mr = wm * 64 + i * 16 + lrow;
            int gx = (k0 >> 3) + (lane >> 4);
            a[i] = *(const bf16x8*)&H1[mr * 256 + ((gx ^ (mr & 7)) << 3)];
        }
#pragma unroll
        for (int j = 0; j < 4; ++j)
            b[j] = *(const bf16x8*)&Bs[buf][(wn * 64 + j * 16 + lrow) * 32 + lk8];
#pragma unroll
        for (int i = 0; i < 4; ++i)
#pragma unroll
            for (int j = 0; j < 4; ++j)
                acc[i][j] = __builtin_amdgcn_mfma_f32_16x16x32_bf16(a[i], b[j], acc[i][j], 0, 0, 0);
    }

    // ---- fc2 epilogue: bias + elu + fused BN2 stats + store ----
    float bv2[4], sv[4], qv[4];
#pragma unroll
    for (int j = 0; j < 4; ++j) {
        bv2[j] = bias2[wn * 64 + j * 16 + lrow];
        sv[j] = 0.f;
        qv[j] = 0.f;
    }
#pragma unroll
    for (int i = 0; i < 4; ++i) {
#pragma unroll
        for (int j = 0; j < 4; ++j) {
            int col = wn * 64 + j * 16 + lrow;
#pragma unroll
            for (int r = 0; r < 4; ++r) {
                int row = m0 + wm * 64 + i * 16 + (lane >> 4) * 4 + r;
                float v = elu(acc[i][j][r] + bv2[j]);
                sv[j] += v;
                qv[j] += v * v;
                out[(size_t)row * 256 + col] = f2bf(v);
            }
        }
    }
#pragma unroll
    for (int j = 0; j < 4; ++j) {
        float s = sv[j], q_ = qv[j];
        s += __shfl_xor(s, 16); q_ += __shfl_xor(q_, 16);
        s += __shfl_xor(s, 32); q_ += __shfl_xor(q_, 32);
        if ((lane >> 4) == 0) {
            int col = wn * 64 + j * 16 + lrow;
            atomicAdd(&stats[col], s);
            atomicAdd(&stats[256 + col], q_);
        }
    }
}

// -------------------- elementwise affine + relu (BN3) ------------------------
__global__ __launch_bounds__(256) void norm_affine_relu(const u16* __restrict__ in,
                                                        const float* __restrict__ scsh,
                                                        u16* __restrict__ out, int n8) {
    int i = blockIdx.x * 256 + threadIdx.x;
    if (i >= n8) return;
    size_t base = (size_t)i * 8;
    int ch8 = (int)(base & 255);
    u16x8 v = *(const u16x8*)(in + base);
    u16x8 o;
#pragma unroll
    for (int e = 0; e < 8; ++e) {
        float f = bf2f(v[e]);
        f = scsh[ch8 + e] * f + scsh[256 + ch8 + e];
        o[e] = f2bf(f > 0.f ? f : 0.f);
    }
    *(u16x8*)(out + base) = o;
}

// -------------------- edge2node: incidence sum + BN2 affine (verified) -------
__global__ __launch_bounds__(256) void edge2node(const u16* __restrict__ h2,
                                                 const float* __restrict__ scsh2,
                                                 u16* __restrict__ n1) {
    int tid = threadIdx.x;
    int row = blockIdx.x * 8 + (tid >> 5);
    int ch8 = (tid & 31) * 8;
    int t = row & 63;
    int bv = row >> 6;
    int v = bv % NV;
    int b = bv / NV;
    float acc[8] = {0, 0, 0, 0, 0, 0, 0, 0};
#pragma unroll
    for (int i = 0; i < 9; ++i) {
        int s = i + (i >= v ? 1 : 0);
        int e = s * 9 + (v < s ? v : v - 1);
        u16x8 vv = *(const u16x8*)(h2 + ((size_t)((b * NE + e) * TT + t)) * 256 + ch8);
#pragma unroll
        for (int k = 0; k < 8; ++k) acc[k] += bf2f(vv[k]);
    }
    const float inv9 = 1.f / 9.f;
    u16x8 o;
#pragma unroll
    for (int k = 0; k < 8; ++k) {
        int c = ch8 + k;
        o[k] = f2bf(scsh2[c] * (acc[k] * inv9) + scsh2[256 + c]);
    }
    *(u16x8*)(n1 + (size_t)row * 256 + ch8) = o;
}

// -------------------- final head: dot(a2_row, wo2) + bo2 (verified) ----------
__global__ __launch_bounds__(256) void head2(const u16* __restrict__ a2,
                                             const u16* __restrict__ wo2t,
                                             const float* __restrict__ bo2,
                                             float* __restrict__ out) {
    int tid = threadIdx.x;
    int row = blockIdx.x * 8 + (tid >> 5);
    int l32 = tid & 31;
    int ch8 = l32 * 8;
    u16x8 a = *(const u16x8*)(a2 + (size_t)row * 256 + ch8);
    u16x8 w = *(const u16x8*)(wo2t + ch8);
    float p = 0.f;
#pragma unroll
    for (int k = 0; k < 8; ++k) p += bf2f(a[k]) * bf2f(w[k]);
#pragma unroll
    for (int off = 16; off > 0; off >>= 1) p += __shfl_down(p, off, 32);
    if (l32 == 0) {
        int b = row / (NV * TT);
        int v = (row >> 6) % NV;
        int t = row & 63;
        out[(size_t)(b * TT + t) * NV + v] = p + bo2[0];
    }
}

extern "C" void kernel_launch(void* const* d_in, const int* in_sizes, int n_in,
                              void* d_out, int out_size, void* d_ws, size_t ws_size,
                              hipStream_t stream) {
    const float* x   = (const float*)d_in[0];
    const float* w1a = (const float*)d_in[1];
    const float* b1a = (const float*)d_in[2];
    const float* w1b = (const float*)d_in[3];
    const float* b1b = (const float*)d_in[4];
    const float* g1  = (const float*)d_in[5];
    const float* be1 = (const float*)d_in[6];
    const float* w2a = (const float*)d_in[7];
    const float* b2a = (const float*)d_in[8];
    const float* w2b = (const float*)d_in[9];
    const float* b2b = (const float*)d_in[10];
    const float* g2  = (const float*)d_in[11];
    const float* be2 = (const float*)d_in[12];
    const float* w3a = (const float*)d_in[13];
    const float* b3a = (const float*)d_in[14];
    const float* w3b = (const float*)d_in[15];
    const float* b3b = (const float*)d_in[16];
    const float* g3  = (const float*)d_in[17];
    const float* be3 = (const float*)d_in[18];
    const float* wo1 = (const float*)d_in[19];
    const float* bo1 = (const float*)d_in[20];
    const float* wo2 = (const float*)d_in[21];
    const float* bo2 = (const float*)d_in[22];
    float* out = (float*)d_out;

    char* ws = (char*)d_ws;
    size_t off = 0;
    auto alloc = [&](size_t bytes) {
        void* p = ws + off;
        off = (off + bytes + 255) & ~(size_t)255;
        return p;
    };
    u16* w1bP = (u16*)alloc(2 * 8 * 4096 * 2);     // 128-tile pack, K=256
    u16* w3aP = (u16*)alloc(2 * 8 * 4096 * 2);
    u16* w3bP = (u16*)alloc(2 * 8 * 4096 * 2);
    u16* wo1P = (u16*)alloc(2 * 8 * 4096 * 2);
    u16* w2aP = (u16*)alloc(16 * 8192 * 2);        // 256-wide pack, K=512 (folded)
    u16* w2bP = (u16*)alloc(8 * 8192 * 2);         // 256-wide pack, K=256
    u16* wo2T = (u16*)alloc(256 * 2);
    float* sums  = (float*)alloc(3 * 512 * 4);
    float* scsh1 = (float*)alloc(512 * 4);
    float* scsh2 = (float*)alloc(512 * 4);
    float* scsh3 = (float*)alloc(512 * 4);
    float* b2aF  = (float*)alloc(256 * 4);
    u16* S0 = (u16*)alloc((size_t)R1 * 256 * 2);
    u16* S1 = (u16*)alloc((size_t)R1 * 256 * 2);
    u16* S2 = (u16*)alloc((size_t)R1 * 256 * 2);
    u16* BIG2 = (u16*)alloc((size_t)R2 * 256 * 2);

    dim3 pgrid(16, 4);
    pack4<<<pgrid, 256, 0, stream>>>(w1b, w1bP, w3a, w3aP, w3b, w3bP, wo1, wo1P);
    pack256<<<8, 256, 0, stream>>>(w2b, w2bP);
    zero_stats<<<6, 256, 0, stream>>>(sums, 3 * 512);
    conv_wo2<<<1, 256, 0, stream>>>(wo2, wo2T);

    // mlp1: fc1 (VALU) + fc2 GEMM with fused stats
    mlp1_fc1<<<R1 / 8, 256, 0, stream>>>(x, w1a, b1a, S0);
    gemm_kernel<1, true><<<(R1 / 128) * 2, 256, 0, stream>>>(S0, w1bP, b1b, S1, 256, sums);
    stats_final<<<1, 256, 0, stream>>>(sums, g1, be1, 1.f / R1, scsh1);
    pack256_w2a<<<16, 256, 0, stream>>>(w2a, scsh1, w2aP);
    fold_b2a<<<256, 256, 0, stream>>>(w2a, scsh1, b2a, b2aF);

    // mlp2: fused gather-fc1 + fc2 (BIG1 eliminated), BN2 stats fused
    mlp2_fused<<<R2 / 128, 512, 0, stream>>>(S1, w2aP, b2aF, w2bP, b2b, BIG2, sums + 512);
    stats_final<<<1, 256, 0, stream>>>(sums + 512, g2, be2, 1.f / R2, scsh2);

    // edge2node (BN2 affine folded in)
    edge2node<<<R1 / 8, 256, 0, stream>>>(BIG2, scsh2, S0);

    // mlp3: two GEMMs, stats fused into fc2
    gemm_kernel<1, false><<<(R1 / 128) * 2, 256, 0, stream>>>(S0, w3aP, b3a, S1, 256, nullptr);
    gemm_kernel<1, true><<<(R1 / 128) * 2, 256, 0, stream>>>(S1, w3bP, b3b, S2, 256, sums + 1024);
    stats_final<<<1, 256, 0, stream>>>(sums + 1024, g3, be3, 1.f / R1, scsh3);

    // head: BN3 affine+relu, wo1 GEMM (relu), dot wo2
    norm_affine_relu<<<(R1 * 32 + 255) / 256, 256, 0, stream>>>(S2, scsh3, S0, R1 * 32);
    gemm_kernel<2, false><<<(R1 / 128) * 2, 256, 0, stream>>>(S0, wo1P, bo1, S1, 256, nullptr);
    head2<<<R1 / 8, 256, 0, stream>>>(S1, wo2T, bo2, out);
}